// Round 13
// baseline (697.020 us; speedup 1.0000x reference)
//
#include <hip/hip_runtime.h>

typedef int v4i __attribute__((ext_vector_type(4)));

static constexpr int K_DIM = 4096;
static constexpr int BM = 256, BN = 128, BK = 64;

// ---------------- per-token dynamic quantization ----------------
__global__ __launch_bounds__(256) void quant_kernel(const float* __restrict__ x,
                                                    signed char* __restrict__ xq,
                                                    float* __restrict__ xs) {
    const int token = blockIdx.x;
    const float4* row = (const float4*)(x + (size_t)token * K_DIM);
    const int t = threadIdx.x;
    float4 v[4];
    float m = 0.f;
#pragma unroll
    for (int i = 0; i < 4; ++i) {
        v[i] = row[t * 4 + i];
        m = fmaxf(m, fabsf(v[i].x));
        m = fmaxf(m, fabsf(v[i].y));
        m = fmaxf(m, fabsf(v[i].z));
        m = fmaxf(m, fabsf(v[i].w));
    }
#pragma unroll
    for (int d = 32; d > 0; d >>= 1) m = fmaxf(m, __shfl_xor(m, d));
    __shared__ float red[4];
    if ((t & 63) == 0) red[t >> 6] = m;
    __syncthreads();
    const float am = fmaxf(fmaxf(red[0], red[1]), fmaxf(red[2], red[3]));
    const float s = fmaxf(am, 1e-8f) * (1.0f / 127.0f);
    const float inv = 127.0f / fmaxf(am, 1e-8f);

    int pk[4];
#pragma unroll
    for (int i = 0; i < 4; ++i) {
        int q0 = (int)fminf(127.f, fmaxf(-127.f, rintf(v[i].x * inv)));
        int q1 = (int)fminf(127.f, fmaxf(-127.f, rintf(v[i].y * inv)));
        int q2 = (int)fminf(127.f, fmaxf(-127.f, rintf(v[i].z * inv)));
        int q3 = (int)fminf(127.f, fmaxf(-127.f, rintf(v[i].w * inv)));
        pk[i] = (q0 & 255) | ((q1 & 255) << 8) | ((q2 & 255) << 16) | (q3 << 24);
    }
    ((int4*)(xq + (size_t)token * K_DIM))[t] = make_int4(pk[0], pk[1], pk[2], pk[3]);
    if (t == 0) xs[token] = s;
}

// ---------------- weight repack: int32 -> packed int8 ----------------
__global__ __launch_bounds__(256) void repack_kernel(const int* __restrict__ w32,
                                                     int4* __restrict__ w8,
                                                     int n16) {
    const int idx = blockIdx.x * 256 + threadIdx.x;
    if (idx >= n16) return;
    const int4* src = (const int4*)w32 + (size_t)idx * 4;
    int4 a = src[0], b = src[1], c = src[2], d = src[3];
    int p0 = (a.x & 255) | ((a.y & 255) << 8) | ((a.z & 255) << 16) | (a.w << 24);
    int p1 = (b.x & 255) | ((b.y & 255) << 8) | ((b.z & 255) << 16) | (b.w << 24);
    int p2 = (c.x & 255) | ((c.y & 255) << 8) | ((c.z & 255) << 16) | (c.w << 24);
    int p3 = (d.x & 255) | ((d.y & 255) << 8) | ((d.z & 255) << 16) | (d.w << 24);
    w8[idx] = make_int4(p0, p1, p2, p3);
}

// ---- int8 MFMA GEMM: 256x128 tile, 4 waves (2x2), wave = 128x64 (0.375 KB
// ---- LDS-read per MFMA -> balanced pipes), BK=64 packed 128-B LDS rows
// ---- (silicon-verified zero-conflict), 3-buf 72 KB -> 2 blocks/CU,
// ---- register-prefetch of next tile's frags under current MFMA cluster,
// ---- counted vmcnt(12) distance-2 verify (never drains mid-loop) ----
__global__ __launch_bounds__(256, 2) void gemm_kernel(const signed char* __restrict__ xq,
                                                      const signed char* __restrict__ w8,
                                                      const float* __restrict__ xs,
                                                      const float* __restrict__ scale,
                                                      const float* __restrict__ bias,
                                                      float* __restrict__ out,
                                                      int N) {
    __shared__ __align__(16) signed char sA[3 * 16384];   // 3 bufs x 16 KB (128 rows x 128 B)
    __shared__ __align__(16) signed char sB[3 * 8192];    // 3 bufs x 8 KB  (64 rows x 128 B)

    const int tid = threadIdx.x;
    const int lane = tid & 63;
    const int wid = tid >> 6;          // 4 waves: 2(M) x 2(N)
    const int wm = wid >> 1;
    const int wn = wid & 1;

    // T1: XCD-aware bijective swizzle (grid = 86 x 32 = 2752, divisible by 8)
    const int nwg = gridDim.x * gridDim.y;
    int flat = blockIdx.y * gridDim.x + blockIdx.x;
    if ((nwg & 7) == 0) flat = (flat & 7) * (nwg >> 3) + (flat >> 3);
    const int by = flat % gridDim.y;          // M fast within chunk -> B panel L2-resident
    const int bx = flat / gridDim.y;
    const int m0 = by * BM;
    const int n0 = bx * BN;

    v4i acc[8][4];
    const v4i vzero = {0, 0, 0, 0};
#pragma unroll
    for (int i = 0; i < 8; ++i)
#pragma unroll
        for (int j = 0; j < 4; ++j) acc[i][j] = vzero;

    // ---- staging sources (verified involution; LDS dest linear) ----
    // A: 256 matrix rows packed as 128 LDS rows x 128 B (pairs r, r+128);
    // B: 128 matrix rows packed as 64 LDS rows x 128 B (pairs r, r+64).
    // LDS row r slot s: s>>2 = packed half, s&3 = k-quarter; phys slot = s ^ (r&7).
    const int lrow = tid >> 3;                       // 0..31 per issue (issue adds +32)
    const int s = (tid & 7) ^ (lrow & 7);            // (+32) preserves row&7
    const signed char* srcA = xq + ((size_t)m0 + lrow + (s >> 2) * 128) * K_DIM + (s & 3) * 16;
    const signed char* srcB = w8 + ((size_t)n0 + lrow + (s >> 2) * 64) * K_DIM + (s & 3) * 16;

    auto stage = [&](int offA, int offB, unsigned int kb) {   // 6 issues x 4 KB
#pragma unroll
        for (int i = 0; i < 4; ++i)
            __builtin_amdgcn_global_load_lds(
                (const __attribute__((address_space(1))) void*)(srcA + (size_t)i * 32 * K_DIM + kb),
                (__attribute__((address_space(3))) void*)&sA[offA + i * 4096 + wid * 1024], 16, 0, 0);
#pragma unroll
        for (int i = 0; i < 2; ++i)
            __builtin_amdgcn_global_load_lds(
                (const __attribute__((address_space(1))) void*)(srcB + (size_t)i * 32 * K_DIM + kb),
                (__attribute__((address_space(3))) void*)&sB[offB + i * 4096 + wid * 1024], 16, 0, 0);
    };

    // ---- read-side per-lane constants (verified zero-conflict pattern) ----
    const int colA = ((wm * 4 + (lane >> 4)) ^ (lane & 7)) << 4;   // wm = packed half of A
    const int colB = ((wn * 4 + (lane >> 4)) ^ (lane & 7)) << 4;   // wn = packed half of B
    const int rowq = (lane & 15) * 128;

    v4i aA[8], bA[4], aB[8], bB[4];   // two frag sets (cur/nxt alternate by body parity)

#define RDFR(AD, BD, OA, OB)                                                   \
    _Pragma("unroll") for (int mi = 0; mi < 8; ++mi)                           \
        AD[mi] = *(const v4i*)&sA[(OA) + rowq + mi * 2048 + colA];             \
    _Pragma("unroll") for (int ni = 0; ni < 4; ++ni)                           \
        BD[ni] = *(const v4i*)&sB[(OB) + rowq + ni * 2048 + colB];
#define MM(AC, BC)                                                             \
    __builtin_amdgcn_s_setprio(1);                                             \
    _Pragma("unroll") for (int mi = 0; mi < 8; ++mi)                           \
    _Pragma("unroll") for (int ni = 0; ni < 4; ++ni)                           \
        acc[mi][ni] = __builtin_amdgcn_mfma_i32_16x16x64_i8(                   \
            AC[mi], BC[ni], acc[mi][ni], 0, 0, 0);                             \
    __builtin_amdgcn_s_setprio(0);
// body: stage(t+3 into freed buf) -> counted vmcnt -> barrier(publish t+1) ->
// prefetch frags(t+1) -> MFMA(t) -> lgkmcnt(0) -> barrier(read-complete fence)
#define BODY(AC, BC, AN, BN_, OAn, OBn, DOSTAGE, OSa, OSb, KB, VMSTR)          \
    {                                                                          \
        if (DOSTAGE) stage((OSa), (OSb), (KB));                                \
        asm volatile("s_waitcnt vmcnt(" VMSTR ")" ::: "memory");               \
        __builtin_amdgcn_s_barrier();                                          \
        RDFR(AN, BN_, OAn, OBn);                                               \
        MM(AC, BC);                                                            \
        asm volatile("s_waitcnt lgkmcnt(0)" ::: "memory");                     \
        __builtin_amdgcn_s_barrier();                                          \
    }

    // ---- prologue: stage tiles 0,1,2 -> bufs 0,1,2; publish t0; prefetch t0 ----
    stage(0, 0, 0);
    stage(16384, 4096 * 2, BK);
    stage(32768, 4096 * 4, 2 * BK);
    asm volatile("s_waitcnt vmcnt(12)" ::: "memory");   // t0's 6 issues landed
    __builtin_amdgcn_s_barrier();
    RDFR(aA, bA, 0, 0);
    asm volatile("s_waitcnt lgkmcnt(0)" ::: "memory");
    __builtin_amdgcn_s_barrier();

    // ---- main loop: bodies 0..59 (10 x 6, static bufs and reg sets) ----
    unsigned int kb = 3 * BK;
    for (int it = 0; it < 10; ++it) {
        BODY(aA, bA, aB, bB, 16384, 8192,  1, 0,     0,     kb,          "12");  // kt=6it+0
        BODY(aB, bB, aA, bA, 32768, 16384, 1, 16384, 8192,  kb + BK,     "12");  // +1
        BODY(aA, bA, aB, bB, 0,     0,     1, 32768, 16384, kb + 2 * BK, "12");  // +2
        BODY(aB, bB, aA, bA, 16384, 8192,  1, 0,     0,     kb + 3 * BK, "12");  // +3
        BODY(aA, bA, aB, bB, 32768, 16384, 1, 16384, 8192,  kb + 4 * BK, "12");  // +4
        BODY(aB, bB, aA, bA, 0,     0,     1, 32768, 16384, kb + 5 * BK, "12");  // +5
        kb += 6 * BK;
    }

    // ---- tail: body 60 stages t63; 61/62 no stage (vm 6/0); 63 pure MFMA ----
    BODY(aA, bA, aB, bB, 16384, 8192,  1, 0, 0, (unsigned int)(63 * BK), "12"); // body 60
    BODY(aB, bB, aA, bA, 32768, 16384, 0, 0, 0, 0u,                      "6");  // body 61
    BODY(aA, bA, aB, bB, 0,     0,     0, 0, 0, 0u,                      "0");  // body 62
    MM(aB, bB);                                                                  // body 63
#undef BODY

    // ---- output epilogue: D reg r of lane l -> row (l>>4)*4+r, col l&15 per frag
    const int mrow0 = m0 + wm * 128 + ((lane >> 4) << 2);
    const int ncol0 = n0 + wn * 64 + (lane & 15);
    float xsv[8][4];
#pragma unroll
    for (int mi = 0; mi < 8; ++mi)
#pragma unroll
        for (int r = 0; r < 4; ++r) xsv[mi][r] = xs[mrow0 + mi * 16 + r];

#pragma unroll
    for (int ni = 0; ni < 4; ++ni) {
        const int n = ncol0 + ni * 16;
        const float sc = scale[n];
        const float bs = bias[n];
#pragma unroll
        for (int mi = 0; mi < 8; ++mi) {
#pragma unroll
            for (int r = 0; r < 4; ++r) {
                const int m = mrow0 + mi * 16 + r;
                out[(size_t)m * N + n] = (float)acc[mi][ni][r] * xsv[mi][r] * sc + bs;
            }
        }
    }
}

extern "C" void kernel_launch(void* const* d_in, const int* in_sizes, int n_in,
                              void* d_out, int out_size, void* d_ws, size_t ws_size,
                              hipStream_t stream) {
    const float* x     = (const float*)d_in[0];
    const int*   w32   = (const int*)d_in[1];
    const float* scale = (const float*)d_in[2];
    const float* bias  = (const float*)d_in[3];
    float* out = (float*)d_out;

    const int M = in_sizes[0] / K_DIM;   // 8192
    const int N = in_sizes[2];           // 11008

    char* ws = (char*)d_ws;
    signed char* xq = (signed char*)ws;                                  // M*K
    float* xs = (float*)(ws + (size_t)M * K_DIM);                        // M floats
    signed char* w8 = (signed char*)(ws + (size_t)M * K_DIM + (size_t)M * sizeof(float));  // N*K

    quant_kernel<<<M, 256, 0, stream>>>(x, xq, xs);

    const int n16 = (N * K_DIM) / 16;
    repack_kernel<<<(n16 + 255) / 256, 256, 0, stream>>>(w32, (int4*)w8, n16);

    gemm_kernel<<<dim3(N / BN, M / BM), 256, 0, stream>>>(xq, w8, xs, scale, bias, out, N);
}

// Round 14
// 555.233 us; speedup vs baseline: 1.2554x; 1.2554x over previous
//
#include <hip/hip_runtime.h>

typedef int v4i __attribute__((ext_vector_type(4)));

static constexpr int K_DIM = 4096;
static constexpr int BM = 128, BN = 256, BK = 64;

// ---------------- per-token dynamic quantization ----------------
__global__ __launch_bounds__(256) void quant_kernel(const float* __restrict__ x,
                                                    signed char* __restrict__ xq,
                                                    float* __restrict__ xs) {
    const int token = blockIdx.x;
    const float4* row = (const float4*)(x + (size_t)token * K_DIM);
    const int t = threadIdx.x;
    float4 v[4];
    float m = 0.f;
#pragma unroll
    for (int i = 0; i < 4; ++i) {
        v[i] = row[t * 4 + i];
        m = fmaxf(m, fabsf(v[i].x));
        m = fmaxf(m, fabsf(v[i].y));
        m = fmaxf(m, fabsf(v[i].z));
        m = fmaxf(m, fabsf(v[i].w));
    }
#pragma unroll
    for (int d = 32; d > 0; d >>= 1) m = fmaxf(m, __shfl_xor(m, d));
    __shared__ float red[4];
    if ((t & 63) == 0) red[t >> 6] = m;
    __syncthreads();
    const float am = fmaxf(fmaxf(red[0], red[1]), fmaxf(red[2], red[3]));
    const float s = fmaxf(am, 1e-8f) * (1.0f / 127.0f);
    const float inv = 127.0f / fmaxf(am, 1e-8f);

    int pk[4];
#pragma unroll
    for (int i = 0; i < 4; ++i) {
        int q0 = (int)fminf(127.f, fmaxf(-127.f, rintf(v[i].x * inv)));
        int q1 = (int)fminf(127.f, fmaxf(-127.f, rintf(v[i].y * inv)));
        int q2 = (int)fminf(127.f, fmaxf(-127.f, rintf(v[i].z * inv)));
        int q3 = (int)fminf(127.f, fmaxf(-127.f, rintf(v[i].w * inv)));
        pk[i] = (q0 & 255) | ((q1 & 255) << 8) | ((q2 & 255) << 16) | (q3 << 24);
    }
    ((int4*)(xq + (size_t)token * K_DIM))[t] = make_int4(pk[0], pk[1], pk[2], pk[3]);
    if (t == 0) xs[token] = s;
}

// ---------------- weight repack: int32 -> packed int8 ----------------
__global__ __launch_bounds__(256) void repack_kernel(const int* __restrict__ w32,
                                                     int4* __restrict__ w8,
                                                     int n16) {
    const int idx = blockIdx.x * 256 + threadIdx.x;
    if (idx >= n16) return;
    const int4* src = (const int4*)w32 + (size_t)idx * 4;
    int4 a = src[0], b = src[1], c = src[2], d = src[3];
    int p0 = (a.x & 255) | ((a.y & 255) << 8) | ((a.z & 255) << 16) | (a.w << 24);
    int p1 = (b.x & 255) | ((b.y & 255) << 8) | ((b.z & 255) << 16) | (b.w << 24);
    int p2 = (c.x & 255) | ((c.y & 255) << 8) | ((c.z & 255) << 16) | (c.w << 24);
    int p3 = (d.x & 255) | ((d.y & 255) << 8) | ((d.z & 255) << 16) | (d.w << 24);
    w8[idx] = make_int4(p0, p1, p2, p3);
}

// ---- int8 MFMA GEMM: R10 structure (128x256 tile, 8 waves 2x4, wave 64x64,
// ---- BK=64 packed 128-B LDS rows, 3-buf 72 KB -> 2 blocks/CU, counted
// ---- vmcnt(6) distance-2 verify) WITHOUT the hard lgkmcnt(0) drain:
// ---- compiler emits fine-grained lgkmcnt so MFMA overlaps ds_read latency ----
__global__ __launch_bounds__(512, 4) void gemm_kernel(const signed char* __restrict__ xq,
                                                      const signed char* __restrict__ w8,
                                                      const float* __restrict__ xs,
                                                      const float* __restrict__ scale,
                                                      const float* __restrict__ bias,
                                                      float* __restrict__ out,
                                                      int N) {
    __shared__ __align__(16) signed char sA[3 * 8192];    // 3 bufs x 8 KB
    __shared__ __align__(16) signed char sB[3 * 16384];   // 3 bufs x 16 KB

    const int tid = threadIdx.x;
    const int lane = tid & 63;
    const int wid = tid >> 6;          // 8 waves: 2(M) x 4(N)
    const int wm = wid >> 2;
    const int wn = wid & 3;

    // T1: XCD-aware bijective swizzle (grid = 43 x 64 = 2752, divisible by 8)
    const int nwg = gridDim.x * gridDim.y;
    int flat = blockIdx.y * gridDim.x + blockIdx.x;
    if ((nwg & 7) == 0) flat = (flat & 7) * (nwg >> 3) + (flat >> 3);
    const int by = flat % gridDim.y;          // M fast within chunk -> B panel L2-resident
    const int bx = flat / gridDim.y;
    const int m0 = by * BM;
    const int n0 = bx * BN;

    v4i acc[4][4];
    const v4i vzero = {0, 0, 0, 0};
#pragma unroll
    for (int i = 0; i < 4; ++i)
#pragma unroll
        for (int j = 0; j < 4; ++j) acc[i][j] = vzero;

    // ---- staging sources (silicon-verified involution; LDS dest linear) ----
    const int srow = tid >> 3;
    const int s = (tid & 7) ^ (srow & 7);
    const signed char* srcA = xq + ((size_t)m0 + srow + (s >> 2) * 64) * K_DIM + (s & 3) * 16;
    const signed char* srcB = w8 + ((size_t)n0 + srow + (s >> 2) * 128) * K_DIM + (s & 3) * 16;

    auto stage = [&](int offA, int offB, unsigned int kb) {   // 3 issues: A, B-lo, B-hi
        __builtin_amdgcn_global_load_lds(
            (const __attribute__((address_space(1))) void*)(srcA + kb),
            (__attribute__((address_space(3))) void*)&sA[offA + wid * 1024], 16, 0, 0);
        __builtin_amdgcn_global_load_lds(
            (const __attribute__((address_space(1))) void*)(srcB + kb),
            (__attribute__((address_space(3))) void*)&sB[offB + wid * 1024], 16, 0, 0);
        __builtin_amdgcn_global_load_lds(
            (const __attribute__((address_space(1))) void*)(srcB + (size_t)64 * K_DIM + kb),
            (__attribute__((address_space(3))) void*)&sB[offB + 8192 + wid * 1024], 16, 0, 0);
    };

    // ---- read-side per-lane constants (silicon-verified zero-conflict) ----
    const int colA = ((wm * 4 + (lane >> 4)) ^ (lane & 7)) << 4;
    const int colB = (((wn >> 1) * 4 + (lane >> 4)) ^ (lane & 7)) << 4;
    const int rowA = (lane & 15) * 128;
    const int rowB = ((wn & 1) * 64 + (lane & 15)) * 128;

    // body: [fence] reads (compiler-scheduled fine-grained lgkmcnt) -> MFMA ->
    // [fence] barrier -> stage(t+3 into just-read buf) -> counted vmcnt -> barrier
#define BODY(OA, OB, DOSTAGE, KB, VMSTR)                                       \
    {                                                                          \
        asm volatile("" ::: "memory");          /* pin reads after publish */  \
        v4i a_[4], b_[4];                                                      \
        _Pragma("unroll") for (int mi = 0; mi < 4; ++mi)                       \
            a_[mi] = *(const v4i*)&sA[(OA) + rowA + mi * 2048 + colA];         \
        _Pragma("unroll") for (int ni = 0; ni < 4; ++ni)                       \
            b_[ni] = *(const v4i*)&sB[(OB) + rowB + ni * 2048 + colB];         \
        __builtin_amdgcn_s_setprio(1);                                         \
        _Pragma("unroll") for (int mi = 0; mi < 4; ++mi)                       \
            _Pragma("unroll") for (int ni = 0; ni < 4; ++ni)                   \
                acc[mi][ni] = __builtin_amdgcn_mfma_i32_16x16x64_i8(           \
                    a_[mi], b_[ni], acc[mi][ni], 0, 0, 0);                     \
        __builtin_amdgcn_s_setprio(0);                                         \
        asm volatile("" ::: "memory");          /* pin reads before barrier */ \
        __builtin_amdgcn_s_barrier();                                          \
        if (DOSTAGE) stage((OA), (OB), (KB));                                  \
        asm volatile("s_waitcnt vmcnt(" VMSTR ")" ::: "memory");               \
        __builtin_amdgcn_s_barrier();                                          \
    }

    // ---- prologue: stage tiles 0,1,2 into bufs 0,1,2; publish tile 0 ----
    stage(0, 0, 0);
    stage(8192, 16384, BK);
    stage(16384, 32768, 2 * BK);
    asm volatile("s_waitcnt vmcnt(6)" ::: "memory");   // tile 0 landed
    __builtin_amdgcn_s_barrier();

    // ---- main loop: bodies 0..59 (20 x 3, static offsets) ----
    unsigned int kb = 3 * BK;   // byte offset of tile being staged this body
    for (int it = 0; it < 20; ++it) {
        BODY(0,     0,     1, kb,          "6");   // body 3it+0: reads buf0
        BODY(8192,  16384, 1, kb + BK,     "6");   // body 3it+1: reads buf1
        BODY(16384, 32768, 1, kb + 2 * BK, "6");   // body 3it+2: reads buf2
        kb += 3 * BK;
    }

    // ---- tail: bodies 60..62 (stage 63 at body 60; waits 6/3/0), body 63 pure ----
    BODY(0,     0,     1, (unsigned int)(63 * BK), "6");   // body 60
    BODY(8192,  16384, 0, 0u,                      "3");   // body 61
    BODY(16384, 32768, 0, 0u,                      "0");   // body 62
    {   // body 63: reads buf0 (tile 63), MFMA only
        asm volatile("" ::: "memory");
        v4i a_[4], b_[4];
#pragma unroll
        for (int mi = 0; mi < 4; ++mi)
            a_[mi] = *(const v4i*)&sA[0 + rowA + mi * 2048 + colA];
#pragma unroll
        for (int ni = 0; ni < 4; ++ni)
            b_[ni] = *(const v4i*)&sB[0 + rowB + ni * 2048 + colB];
        __builtin_amdgcn_s_setprio(1);
#pragma unroll
        for (int mi = 0; mi < 4; ++mi)
#pragma unroll
            for (int ni = 0; ni < 4; ++ni)
                acc[mi][ni] = __builtin_amdgcn_mfma_i32_16x16x64_i8(
                    a_[mi], b_[ni], acc[mi][ni], 0, 0, 0);
        __builtin_amdgcn_s_setprio(0);
    }
#undef BODY

    // ---- output epilogue: D reg r of lane l -> row (l>>4)*4+r, col l&15 per frag
    const int mrow0 = m0 + wm * 64 + ((lane >> 4) << 2);
    const int ncol0 = n0 + wn * 64 + (lane & 15);
    float xsv[4][4];
#pragma unroll
    for (int mi = 0; mi < 4; ++mi)
#pragma unroll
        for (int r = 0; r < 4; ++r) xsv[mi][r] = xs[mrow0 + mi * 16 + r];

#pragma unroll
    for (int ni = 0; ni < 4; ++ni) {
        const int n = ncol0 + ni * 16;
        const float sc = scale[n];
        const float bs = bias[n];
#pragma unroll
        for (int mi = 0; mi < 4; ++mi) {
#pragma unroll
            for (int r = 0; r < 4; ++r) {
                const int m = mrow0 + mi * 16 + r;
                out[(size_t)m * N + n] = (float)acc[mi][ni][r] * xsv[mi][r] * sc + bs;
            }
        }
    }
}

extern "C" void kernel_launch(void* const* d_in, const int* in_sizes, int n_in,
                              void* d_out, int out_size, void* d_ws, size_t ws_size,
                              hipStream_t stream) {
    const float* x     = (const float*)d_in[0];
    const int*   w32   = (const int*)d_in[1];
    const float* scale = (const float*)d_in[2];
    const float* bias  = (const float*)d_in[3];
    float* out = (float*)d_out;

    const int M = in_sizes[0] / K_DIM;   // 8192
    const int N = in_sizes[2];           // 11008

    char* ws = (char*)d_ws;
    signed char* xq = (signed char*)ws;                                  // M*K
    float* xs = (float*)(ws + (size_t)M * K_DIM);                        // M floats
    signed char* w8 = (signed char*)(ws + (size_t)M * K_DIM + (size_t)M * sizeof(float));  // N*K

    quant_kernel<<<M, 256, 0, stream>>>(x, xq, xs);

    const int n16 = (N * K_DIM) / 16;
    repack_kernel<<<(n16 + 255) / 256, 256, 0, stream>>>(w32, (int4*)w8, n16);

    gemm_kernel<<<dim3(N / BN, M / BM), 512, 0, stream>>>(xq, w8, xs, scale, bias, out, N);
}